// Round 4
// baseline (417.803 us; speedup 1.0000x reference)
//
#include <hip/hip_runtime.h>

// GPR-GNN: out = b_fc + sum_k temp[k] * A_hat^k (MLP(x) @ W_fc)
// Trick 1: project features to scalar BEFORE propagation (linearity) -> 1 float/node.
// Trick 2: per-edge GLOBAL atomics cost ~35B memory-side RMW (measured R2/R3)
//          -> per-edge atomics are LDS-only.
// Trick 3: u-space propagation u_k = D^{-1/2} z_k -> per-edge work is one
//          unweighted gather+add.
// Trick 4: bucketing = two-level counting sort (98 super-buckets of 1024 nodes).
// Trick 6: PUSH-accumulate hops. Pass-2 sorts each dst-bucket's edges by SRC
//          super-bucket (98-bin sort). Hop = LDS 1024-slot accumulator per
//          dst-bucket chunk; chunks are CONTIGUOUS in src-sorted order, so each
//          4096-edge chunk spans only ~12 src buckets (~392 lines, ~10 edges/line)
//          -> u-gather L2 line traffic ~422MB -> ~39MB per hop. 8 chunk-blocks
//          per bucket (784 blocks) avoids R10's parallelism cliff; partials
//          merged via ~800K coalesced fp32 global atomics into L2-resident gacc.
// Trick 7: ebuf2 buckets padded to x4 with sentinel (n<<10) edges; u[n]=0 dummy
//          -> k_acc reads ONE aligned uint4 of indices per thread, no guards.
// ANTI-LESSON (R8): cooperative grid.sync ~125us each on 8-XCD MI355X. Never.
// ANTI-LESSON (R9): MLP fused into scatter adds ~20us serial wave chains ->
//          separate thread-per-node register-blocked MLP.
// ANTI-LESSON (R10): LDS-tiled SpMV with 1 block/bucket = parallelism cliff.

#define TPB  256
#define TSC  512             // scatter block threads
#define SBSH 10              // 1024 nodes per super-bucket
#define CAP1 37376           // bucket capacity (mean 32768, ~25 sigma; mult of 4)
#define EPT  8               // edges per thread in pass 1
#define CH   (TSC * EPT)     // 4096 edges per scatter block
#define CPB  8               // chunk-blocks per super-bucket in k_acc

// ---- MLP (thread per node, register-blocked) + bcursor zeroing ----
__global__ void k_mlp(const float* __restrict__ x, const float* __restrict__ W1,
                      const float* __restrict__ b1, const float* __restrict__ W2,
                      const float* __restrict__ b2, const float* __restrict__ Wfc,
                      float* __restrict__ zarr, int* __restrict__ bcursor, int n) {
    int i = blockIdx.x * blockDim.x + threadIdx.x;
    if (i < 128) bcursor[i] = 0;
    if (i >= n) return;
    float xv = x[i];
    float h1[32];
#pragma unroll
    for (int j = 0; j < 32; j++)
        h1[j] = fmaxf(fmaf(xv, W1[j], b1[j]), 0.f);
    float z = 0.f;
#pragma unroll
    for (int fc = 0; fc < 4; fc++) {
        float acc[16];
#pragma unroll
        for (int f = 0; f < 16; f++) acc[f] = b2[fc * 16 + f];
#pragma unroll
        for (int j = 0; j < 32; j++) {
            float h = h1[j];
#pragma unroll
            for (int f = 0; f < 16; f++)
                acc[f] = fmaf(h, W2[j * 64 + fc * 16 + f], acc[f]);
        }
#pragma unroll
        for (int f = 0; f < 16; f++)
            z = fmaf(fmaxf(acc[f], 0.f), Wfc[fc * 16 + f], z);
    }
    zarr[i] = z;
}

// ---- Pass 1: bucket edges into 98 super-buckets, packed (src<<10)|dst10 ----
__global__ void __launch_bounds__(TSC)
k_scatter(const int* __restrict__ erow, const int* __restrict__ ecol,
          int* __restrict__ bcursor, unsigned int* __restrict__ ebuf1,
          int e, int nsb) {
    __shared__ int hist[128];
    __shared__ int base[128];
    int t = threadIdx.x;
    int s = blockIdx.x * CH;
    int r[EPT], c[EPT];

    if (t < 128) hist[t] = 0;
    __syncthreads();
#pragma unroll
    for (int j = 0; j < EPT; j++) {
        int i = s + j * TSC + t;
        bool ok = (i < e);
        c[j] = ok ? ecol[i] : -1;
        r[j] = ok ? erow[i] : 0;
        if (ok) atomicAdd(&hist[c[j] >> SBSH], 1);
    }
    __syncthreads();
    if (t < nsb) {
        int cc = hist[t];
        base[t] = cc ? atomicAdd(&bcursor[t], cc) : 0;
        hist[t] = 0;    // reuse as local cursor
    }
    __syncthreads();
#pragma unroll
    for (int j = 0; j < EPT; j++) {
        if (c[j] >= 0) {
            int b = c[j] >> SBSH;
            int pos = base[b] + atomicAdd(&hist[b], 1);
            if (pos < CAP1)
                ebuf1[(size_t)b * CAP1 + pos] =
                    ((unsigned int)r[j] << SBSH) | (unsigned int)(c[j] & 1023);
        }
    }
}

// ---- Pass 2: one 1024-thread block per super-bucket.
// (a) LDS histograms: 1024-bin dst (degrees) + 128-bin src-super-bucket.
// (b) 128-bin exclusive scan (2-wave shuffle).
// (c) node init: nrm {1/d, sqrt(d)}, u0 = z/sqrt(d), out = b_fc + temp0*z;
//     zero gacc; dummy slot u[n]=0.
// (d) scatter edges into ebuf2 sorted by src super-bucket (gather locality);
//     pad bucket tail to x4 with sentinel (n<<10) edges. ----
__global__ void __launch_bounds__(1024)
k_sub(const int* __restrict__ bcursor, const unsigned int* __restrict__ ebuf1,
      unsigned int* __restrict__ ebuf2, float2* __restrict__ nrm,
      const float* __restrict__ zarr, const float* __restrict__ temp,
      const float* __restrict__ bfc, float* __restrict__ u0,
      float* __restrict__ u1, float* __restrict__ gacc,
      float* __restrict__ out, int n) {
    __shared__ int hist[1024];
    __shared__ int h2[128];
    __shared__ int base2[128];
    __shared__ int carry;
    int b = blockIdx.x;
    int t = threadIdx.x;
    int lane = t & 63;
    int w = t >> 6;

    hist[t] = 0;
    if (t < 128) h2[t] = 0;
    __syncthreads();
    int cnt = min(bcursor[b], CAP1);
    size_t g = (size_t)b * CAP1;
    int last = cnt > 0 ? cnt - 1 : 0;
    for (int j = t; j < cnt; j += 4096) {
        int j1 = j + 1024, j2 = j + 2048, j3 = j + 3072;
        unsigned int p0 = ebuf1[g + j];
        unsigned int p1 = ebuf1[g + min(j1, last)];
        unsigned int p2 = ebuf1[g + min(j2, last)];
        unsigned int p3 = ebuf1[g + min(j3, last)];
        atomicAdd(&hist[p0 & 1023], 1);
        atomicAdd(&h2[p0 >> 20], 1);
        if (j1 < cnt) { atomicAdd(&hist[p1 & 1023], 1); atomicAdd(&h2[p1 >> 20], 1); }
        if (j2 < cnt) { atomicAdd(&hist[p2 & 1023], 1); atomicAdd(&h2[p2 >> 20], 1); }
        if (j3 < cnt) { atomicAdd(&hist[p3 & 1023], 1); atomicAdd(&h2[p3 >> 20], 1); }
    }
    __syncthreads();

    // exclusive scan of h2[0..127]; waves 0/1 carry real data
    int v128 = (t < 128) ? h2[t] : 0;
    int sv = v128;
#pragma unroll
    for (int o = 1; o < 64; o <<= 1) {
        int uu = __shfl_up(sv, o);
        if (lane >= o) sv += uu;
    }
    if (t == 63) carry = sv;          // total of bins 0..63
    __syncthreads();
    if (t < 128) {
        base2[t] = sv - v128 + (w == 1 ? carry : 0);
        h2[t] = 0;                    // reuse as cursor
    }

    // per-node init + gacc zero
    int node = (b << SBSH) + t;
    float dg = (float)(hist[t] + 1);  // +1 self-loop
    if (node < n) {
        float di = rsqrtf(dg);
        nrm[node] = make_float2(di * di, dg * di);   // {1/d, sqrt(d)}
        float z = zarr[node];
        u0[node] = di * z;
        out[node] = fmaf(temp[0], z, bfc[0]);
    }
    gacc[((size_t)b << SBSH) + t] = 0.f;
    if (b == 0 && t == 0) { u0[n] = 0.f; u1[n] = 0.f; }   // dummy gather slot
    __syncthreads();

    // scatter into src-super-bucket-sorted order
    for (int j = t; j < cnt; j += 4096) {
        int j1 = j + 1024, j2 = j + 2048, j3 = j + 3072;
        unsigned int p0 = ebuf1[g + j];
        unsigned int p1 = ebuf1[g + min(j1, last)];
        unsigned int p2 = ebuf1[g + min(j2, last)];
        unsigned int p3 = ebuf1[g + min(j3, last)];
        int q0 = base2[p0 >> 20] + atomicAdd(&h2[p0 >> 20], 1);
        ebuf2[g + q0] = p0;
        if (j1 < cnt) { int q = base2[p1 >> 20] + atomicAdd(&h2[p1 >> 20], 1); ebuf2[g + q] = p1; }
        if (j2 < cnt) { int q = base2[p2 >> 20] + atomicAdd(&h2[p2 >> 20], 1); ebuf2[g + q] = p2; }
        if (j3 < cnt) { int q = base2[p3 >> 20] + atomicAdd(&h2[p3 >> 20], 1); ebuf2[g + q] = p3; }
    }
    // pad bucket tail to multiple of 4 with sentinel edges -> u[n]=0, dst bits 0.
    // Pad slots are >= cnt; scatter writes only positions < cnt, so no race.
    if (t < ((4 - (cnt & 3)) & 3))
        ebuf2[g + cnt + t] = ((unsigned int)n) << SBSH;
}

// ---- Hop accumulate: 8 chunk-blocks per dst-bucket. Chunks are contiguous in
// src-sorted order -> each spans ~12 src buckets; gathers get ~10 uses per
// 128B line, L1-resident window. One aligned uint4 index load per thread,
// guard-free (sentinel padding). Per-edge add = LDS atomic; block partials
// merge with coalesced fp32 global atomics into gacc (L2-resident, 400KB). ----
__global__ void __launch_bounds__(256)
k_acc(const int* __restrict__ bcursor, const unsigned int* __restrict__ ebuf2,
      const float* __restrict__ u, float* __restrict__ gacc) {
    __shared__ float acc[1024];
    int b = blockIdx.x / CPB;
    int chunk = blockIdx.x % CPB;
    int t = threadIdx.x;
#pragma unroll
    for (int i = t; i < 1024; i += 256) acc[i] = 0.f;
    __syncthreads();
    int cnt4 = (min(bcursor[b], CAP1) + 3) & ~3;          // sentinel-padded count
    int per = (((cnt4 + CPB - 1) / CPB) + 3) & ~3;        // mult of 4 -> aligned
    int s = chunk * per;
    int epos = min(s + per, cnt4);
    size_t g = (size_t)b * CAP1;
    for (int i = s + 4 * t; i < epos; i += 1024) {
        uint4 pp = *(const uint4*)(ebuf2 + g + i);        // 16B-aligned
        float v0 = u[pp.x >> 10];
        float v1 = u[pp.y >> 10];
        float v2 = u[pp.z >> 10];
        float v3 = u[pp.w >> 10];
        atomicAdd(&acc[pp.x & 1023], v0);
        atomicAdd(&acc[pp.y & 1023], v1);
        atomicAdd(&acc[pp.z & 1023], v2);
        atomicAdd(&acc[pp.w & 1023], v3);
    }
    __syncthreads();
    float* gb = gacc + ((size_t)b << SBSH);
#pragma unroll
    for (int i = t; i < 1024; i += 256)
        atomicAdd(&gb[i], acc[i]);
}

// ---- Hop finalize: u_k = (1/d)*(sum + u_{k-1}); out += temp[k]*sqrt(d)*u_k;
// re-zero gacc for the next hop. ----
__global__ void k_fin(float* __restrict__ gacc, const float2* __restrict__ nrm,
                      const float* __restrict__ uin, float* __restrict__ uout,
                      float* __restrict__ out, const float* __restrict__ temp,
                      int k, int n, int is_last) {
    int i = blockIdx.x * blockDim.x + threadIdx.x;
    if (i >= n) return;
    float s = gacc[i];
    gacc[i] = 0.f;
    float2 nv = nrm[i];
    float uk = nv.x * (s + uin[i]);     // self-loop term + gathered sum
    if (!is_last) uout[i] = uk;
    out[i] = fmaf(temp[k] * nv.y, uk, out[i]);
}

static inline size_t align256(size_t v) { return (v + 255) & ~(size_t)255; }

extern "C" void kernel_launch(void* const* d_in, const int* in_sizes, int n_in,
                              void* d_out, int out_size, void* d_ws, size_t ws_size,
                              hipStream_t stream) {
    const float* x    = (const float*)d_in[0];
    const int*   ei   = (const int*)d_in[1];
    const float* W1   = (const float*)d_in[2];
    const float* b1   = (const float*)d_in[3];
    const float* W2   = (const float*)d_in[4];
    const float* b2   = (const float*)d_in[5];
    const float* temp = (const float*)d_in[6];
    const float* Wfc  = (const float*)d_in[7];
    const float* bfc  = (const float*)d_in[8];

    const int n = in_sizes[0];        // 100000 nodes
    const int e = in_sizes[1] / 2;    // 3.2M edges
    const int K = in_sizes[6] - 1;    // 10 hops
    const int nsb = (n + (1 << SBSH) - 1) >> SBSH;   // 98 super-buckets

    const int* erow = ei;             // edge_index[0] = source
    const int* ecol = ei + e;         // edge_index[1] = target

    float* out = (float*)d_out;

    // workspace carve (~31.7 MB)
    char* ws = (char*)d_ws;
    int*          bcursor = (int*)ws;          ws += align256((size_t)128 * 4);
    unsigned int* ebuf1   = (unsigned int*)ws; ws += align256((size_t)nsb * CAP1 * 4);
    unsigned int* ebuf2   = (unsigned int*)ws; ws += align256((size_t)nsb * CAP1 * 4);
    float2*       nrm     = (float2*)ws;       ws += align256((size_t)n * 8);
    float*        zarr    = (float*)ws;        ws += align256((size_t)(n + 1) * 4);
    float*        u0      = (float*)ws;        ws += align256((size_t)(n + 1) * 4);
    float*        u1      = (float*)ws;        ws += align256((size_t)(n + 1) * 4);
    float*        gacc    = (float*)ws;        ws += align256((size_t)nsb * 1024 * 4);

    const int gM = (n + TPB - 1) / TPB;          // 391 MLP blocks
    const int gS = (e + CH - 1) / CH;            // 782 scatter blocks
    const int gF = (n + TPB - 1) / TPB;          // finalize blocks

    k_mlp<<<gM, TPB, 0, stream>>>(x, W1, b1, W2, b2, Wfc, zarr, bcursor, n);
    k_scatter<<<gS, TSC, 0, stream>>>(erow, ecol, bcursor, ebuf1, e, nsb);
    k_sub<<<nsb, 1024, 0, stream>>>(bcursor, ebuf1, ebuf2, nrm, zarr, temp, bfc,
                                    u0, u1, gacc, out, n);

    float* uin = u0;
    float* uout = u1;
    for (int k = 1; k <= K; k++) {
        k_acc<<<nsb * CPB, 256, 0, stream>>>(bcursor, ebuf2, uin, gacc);
        k_fin<<<gF, TPB, 0, stream>>>(gacc, nrm, uin, uout, out, temp,
                                      k, n, (k == K) ? 1 : 0);
        float* t2 = uin; uin = uout; uout = t2;
    }
}